// Round 1
// baseline (462.989 us; speedup 1.0000x reference)
//
#include <hip/hip_runtime.h>
#include <math.h>

#define NB 32
#define NN 512
#define ROWC 2048ull

constexpr int TILE = 64;
constexpr int BK = 32;

__device__ __forceinline__ float wave_red_max(float v) {
#pragma unroll
  for (int o = 32; o > 0; o >>= 1) v = fmaxf(v, __shfl_down(v, o));
  return v;
}
__device__ __forceinline__ float wave_red_sum(float v) {
#pragma unroll
  for (int o = 32; o > 0; o >>= 1) v += __shfl_down(v, o);
  return v;
}

// ---------------- Kernel 1: e[b,p,h] = sum_d px[b,p,d] * hx[b,h,d] ----------
__global__ __launch_bounds__(256) void gemm_nt(const float* __restrict__ A,
                                               const float* __restrict__ Bt,
                                               float* __restrict__ C) {
  __shared__ float As[TILE][BK + 1];
  __shared__ float Bs[TILE][BK + 1];
  const int b = blockIdx.z;
  const float* Ab = A + (size_t)b * NN * NN;
  const float* Bb = Bt + (size_t)b * NN * NN;
  float* Cb = C + (size_t)b * NN * NN;
  const int row0 = blockIdx.y * TILE, col0 = blockIdx.x * TILE;
  const int tid = threadIdx.x;
  const int tx = tid & 15, ty = tid >> 4;
  const int lr = tid >> 3, lc = (tid & 7) * 4;
  float acc[4][4] = {};
  for (int k0 = 0; k0 < NN; k0 += BK) {
    float4 a0 = *(const float4*)&Ab[(size_t)(row0 + lr) * NN + k0 + lc];
    float4 a1 = *(const float4*)&Ab[(size_t)(row0 + lr + 32) * NN + k0 + lc];
    float4 b0 = *(const float4*)&Bb[(size_t)(col0 + lr) * NN + k0 + lc];
    float4 b1 = *(const float4*)&Bb[(size_t)(col0 + lr + 32) * NN + k0 + lc];
    As[lr][lc] = a0.x; As[lr][lc + 1] = a0.y; As[lr][lc + 2] = a0.z; As[lr][lc + 3] = a0.w;
    As[lr + 32][lc] = a1.x; As[lr + 32][lc + 1] = a1.y; As[lr + 32][lc + 2] = a1.z; As[lr + 32][lc + 3] = a1.w;
    Bs[lr][lc] = b0.x; Bs[lr][lc + 1] = b0.y; Bs[lr][lc + 2] = b0.z; Bs[lr][lc + 3] = b0.w;
    Bs[lr + 32][lc] = b1.x; Bs[lr + 32][lc + 1] = b1.y; Bs[lr + 32][lc + 2] = b1.z; Bs[lr + 32][lc + 3] = b1.w;
    __syncthreads();
#pragma unroll
    for (int k = 0; k < BK; ++k) {
      float av[4], bv[4];
#pragma unroll
      for (int i = 0; i < 4; ++i) av[i] = As[ty * 4 + i][k];
#pragma unroll
      for (int j = 0; j < 4; ++j) bv[j] = Bs[tx * 4 + j][k];
#pragma unroll
      for (int i = 0; i < 4; ++i)
#pragma unroll
        for (int j = 0; j < 4; ++j) acc[i][j] = fmaf(av[i], bv[j], acc[i][j]);
    }
    __syncthreads();
  }
#pragma unroll
  for (int i = 0; i < 4; ++i) {
    float4 v = {acc[i][0], acc[i][1], acc[i][2], acc[i][3]};
    *(float4*)&Cb[(size_t)(row0 + ty * 4 + i) * NN + col0 + tx * 4] = v;
  }
}

// ---------------- Kernel 2: wb = softmax over h of (e + h_bias) -------------
__global__ __launch_bounds__(256) void softmax_h_kernel(const float* __restrict__ e,
                                                        const int* __restrict__ h_mask,
                                                        float* __restrict__ wb) {
  const int bp = blockIdx.x;
  const int b = bp >> 9;
  const float* row = e + (size_t)bp * NN;
  float* out = wb + (size_t)bp * NN;
  const int* hm = h_mask + (size_t)b * NN;
  const int t = threadIdx.x;
  const float v0 = hm[t] ? -INFINITY : row[t];
  const float v1 = hm[t + 256] ? -INFINITY : row[t + 256];
  __shared__ float pm[4], ps[4];
  float m = wave_red_max(fmaxf(v0, v1));
  if ((t & 63) == 0) pm[t >> 6] = m;
  __syncthreads();
  m = fmaxf(fmaxf(pm[0], pm[1]), fmaxf(pm[2], pm[3]));
  const float e0 = expf(v0 - m), e1 = expf(v1 - m);
  float s = wave_red_sum(e0 + e1);
  if ((t & 63) == 0) ps[t >> 6] = s;
  __syncthreads();
  s = ps[0] + ps[1] + ps[2] + ps[3];
  const float inv = 1.0f / s;
  out[t] = e0 * inv;
  out[t + 256] = e1 * inv;
}

// ------------- Kernel 3: wa = softmax over p of (e + p_bias), in-place ------
__global__ __launch_bounds__(256) void softmax_p_kernel(float* __restrict__ e,
                                                        const int* __restrict__ p_mask) {
  const int b = blockIdx.y;
  const int h0 = blockIdx.x * 32;
  const int t = threadIdx.x;
  const int tx = t & 31, tyy = t >> 5;
  float* eb = e + (size_t)b * NN * NN;
  const int* pmask = p_mask + (size_t)b * NN;
  const int h = h0 + tx;
  float val[64];
  float m = -INFINITY;
#pragma unroll
  for (int k = 0; k < 64; ++k) {
    const int p = tyy + (k << 3);
    float v = pmask[p] ? -INFINITY : eb[(size_t)p * NN + h];
    val[k] = v;
    m = fmaxf(m, v);
  }
  __shared__ float rm[8][32], rs[8][32];
  rm[tyy][tx] = m;
  __syncthreads();
  if (tyy == 0) {
    float mm = rm[0][tx];
#pragma unroll
    for (int r = 1; r < 8; ++r) mm = fmaxf(mm, rm[r][tx]);
    rm[0][tx] = mm;
  }
  __syncthreads();
  m = rm[0][tx];
  float s = 0.f;
#pragma unroll
  for (int k = 0; k < 64; ++k) {
    val[k] = expf(val[k] - m);
    s += val[k];
  }
  rs[tyy][tx] = s;
  __syncthreads();
  if (tyy == 0) {
    float ss = rs[0][tx];
#pragma unroll
    for (int r = 1; r < 8; ++r) ss += rs[r][tx];
    rs[0][tx] = ss;
  }
  __syncthreads();
  const float inv = 1.0f / rs[0][tx];
#pragma unroll
  for (int k = 0; k < 64; ++k) {
    const int p = tyy + (k << 3);
    eb[(size_t)p * NN + h] = val[k] * inv;
  }
}

// ------- Kernel 4: px_hat = wb @ hx ; fused write of m_p (4 segments) -------
__global__ __launch_bounds__(256) void gemm_nn_mp(const float* __restrict__ W,
                                                  const float* __restrict__ V,
                                                  const float* __restrict__ Px,
                                                  float* __restrict__ mp) {
  __shared__ float Ws[TILE][BK + 1];
  __shared__ float Vs[BK][TILE + 4];
  const int b = blockIdx.z;
  const float* Wb = W + (size_t)b * NN * NN;
  const float* Vb = V + (size_t)b * NN * NN;
  const float* Pxb = Px + (size_t)b * NN * NN;
  const int row0 = blockIdx.y * TILE, col0 = blockIdx.x * TILE;
  const int tid = threadIdx.x;
  const int tx = tid & 15, ty = tid >> 4;
  const int lr = tid >> 3, lc = (tid & 7) * 4;
  const int vk = tid >> 4, vc = (tid & 15) * 4;
  float acc[4][4] = {};
  for (int k0 = 0; k0 < NN; k0 += BK) {
    float4 w0 = *(const float4*)&Wb[(size_t)(row0 + lr) * NN + k0 + lc];
    float4 w1 = *(const float4*)&Wb[(size_t)(row0 + lr + 32) * NN + k0 + lc];
    float4 v0 = *(const float4*)&Vb[(size_t)(k0 + vk) * NN + col0 + vc];
    float4 v1 = *(const float4*)&Vb[(size_t)(k0 + vk + 16) * NN + col0 + vc];
    Ws[lr][lc] = w0.x; Ws[lr][lc + 1] = w0.y; Ws[lr][lc + 2] = w0.z; Ws[lr][lc + 3] = w0.w;
    Ws[lr + 32][lc] = w1.x; Ws[lr + 32][lc + 1] = w1.y; Ws[lr + 32][lc + 2] = w1.z; Ws[lr + 32][lc + 3] = w1.w;
    *(float4*)&Vs[vk][vc] = v0;
    *(float4*)&Vs[vk + 16][vc] = v1;
    __syncthreads();
#pragma unroll
    for (int k = 0; k < BK; ++k) {
      float av[4];
#pragma unroll
      for (int i = 0; i < 4; ++i) av[i] = Ws[ty * 4 + i][k];
      float4 bv = *(const float4*)&Vs[k][tx * 4];
#pragma unroll
      for (int i = 0; i < 4; ++i) {
        acc[i][0] = fmaf(av[i], bv.x, acc[i][0]);
        acc[i][1] = fmaf(av[i], bv.y, acc[i][1]);
        acc[i][2] = fmaf(av[i], bv.z, acc[i][2]);
        acc[i][3] = fmaf(av[i], bv.w, acc[i][3]);
      }
    }
    __syncthreads();
  }
#pragma unroll
  for (int i = 0; i < 4; ++i) {
    const int p = row0 + ty * 4 + i;
    const int d = col0 + tx * 4;
    float4 pxv = *(const float4*)&Pxb[(size_t)p * NN + d];
    float4 ph = {acc[i][0], acc[i][1], acc[i][2], acc[i][3]};
    const size_t base = ((size_t)b * NN + p) * ROWC;
    *(float4*)&mp[base + d] = pxv;
    *(float4*)&mp[base + 512 + d] = ph;
    float4 df = {pxv.x - ph.x, pxv.y - ph.y, pxv.z - ph.z, pxv.w - ph.w};
    *(float4*)&mp[base + 1024 + d] = df;
    float4 pr = {pxv.x * ph.x, pxv.y * ph.y, pxv.z * ph.z, pxv.w * ph.w};
    *(float4*)&mp[base + 1536 + d] = pr;
  }
}

// ------ Kernel 5: hx_hat[h,d] = sum_p wa[p,h]*px[p,d]; fused m_h write ------
__global__ __launch_bounds__(256) void gemm_tn_mh(const float* __restrict__ Wa,
                                                  const float* __restrict__ X,
                                                  const float* __restrict__ Hx,
                                                  float* __restrict__ mh) {
  __shared__ float As[BK][TILE + 4];
  __shared__ float Bs[BK][TILE + 4];
  const int b = blockIdx.z;
  const float* Wb = Wa + (size_t)b * NN * NN;
  const float* Xb = X + (size_t)b * NN * NN;
  const float* Hb = Hx + (size_t)b * NN * NN;
  const int row0 = blockIdx.y * TILE;  // h
  const int col0 = blockIdx.x * TILE;  // d
  const int tid = threadIdx.x;
  const int tx = tid & 15, ty = tid >> 4;
  const int vk = tid >> 4, vc = (tid & 15) * 4;
  float acc[4][4] = {};
  for (int k0 = 0; k0 < NN; k0 += BK) {
    float4 a0 = *(const float4*)&Wb[(size_t)(k0 + vk) * NN + row0 + vc];
    float4 a1 = *(const float4*)&Wb[(size_t)(k0 + vk + 16) * NN + row0 + vc];
    float4 b0 = *(const float4*)&Xb[(size_t)(k0 + vk) * NN + col0 + vc];
    float4 b1 = *(const float4*)&Xb[(size_t)(k0 + vk + 16) * NN + col0 + vc];
    *(float4*)&As[vk][vc] = a0;
    *(float4*)&As[vk + 16][vc] = a1;
    *(float4*)&Bs[vk][vc] = b0;
    *(float4*)&Bs[vk + 16][vc] = b1;
    __syncthreads();
#pragma unroll
    for (int k = 0; k < BK; ++k) {
      float4 av = *(const float4*)&As[k][ty * 4];
      float4 bv = *(const float4*)&Bs[k][tx * 4];
      float a[4] = {av.x, av.y, av.z, av.w};
#pragma unroll
      for (int i = 0; i < 4; ++i) {
        acc[i][0] = fmaf(a[i], bv.x, acc[i][0]);
        acc[i][1] = fmaf(a[i], bv.y, acc[i][1]);
        acc[i][2] = fmaf(a[i], bv.z, acc[i][2]);
        acc[i][3] = fmaf(a[i], bv.w, acc[i][3]);
      }
    }
    __syncthreads();
  }
#pragma unroll
  for (int i = 0; i < 4; ++i) {
    const int h = row0 + ty * 4 + i;
    const int d = col0 + tx * 4;
    float4 hxv = *(const float4*)&Hb[(size_t)h * NN + d];
    float4 hh = {acc[i][0], acc[i][1], acc[i][2], acc[i][3]};
    const size_t base = ((size_t)b * NN + h) * ROWC;
    *(float4*)&mh[base + d] = hxv;
    *(float4*)&mh[base + 512 + d] = hh;
    float4 df = {hxv.x - hh.x, hxv.y - hh.y, hxv.z - hh.z, hxv.w - hh.w};
    *(float4*)&mh[base + 1024 + d] = df;
    float4 pr = {hxv.x * hh.x, hxv.y * hh.y, hxv.z * hh.z, hxv.w * hh.w};
    *(float4*)&mh[base + 1536 + d] = pr;
  }
}

extern "C" void kernel_launch(void* const* d_in, const int* in_sizes, int n_in,
                              void* d_out, int out_size, void* d_ws, size_t ws_size,
                              hipStream_t stream) {
  const float* px = (const float*)d_in[0];
  const float* hx = (const float*)d_in[1];
  const int* p_mask = (const int*)d_in[2];
  const int* h_mask = (const int*)d_in[3];
  float* out = (float*)d_out;

  float* e = (float*)d_ws;                      // 32 MB: scores, then wa in-place
  float* wb = e + (size_t)NB * NN * NN;         // 32 MB: softmax over h

  dim3 blk(256);
  dim3 g1(NN / TILE, NN / TILE, NB);
  gemm_nt<<<g1, blk, 0, stream>>>(px, hx, e);
  softmax_h_kernel<<<dim3(NB * NN), blk, 0, stream>>>(e, h_mask, wb);
  softmax_p_kernel<<<dim3(NN / 32, NB), blk, 0, stream>>>(e, p_mask);
  gemm_nn_mp<<<g1, blk, 0, stream>>>(wb, hx, px, out);
  gemm_tn_mh<<<g1, blk, 0, stream>>>(e, px, hx, out + (size_t)NB * NN * ROWC);
}

// Round 2
// 242.611 us; speedup vs baseline: 1.9084x; 1.9084x over previous
//
#include <hip/hip_runtime.h>
#include <math.h>

#define NB 32
#define NN 512
#define ROWC 2048ull

typedef __attribute__((ext_vector_type(8))) short bf16x8;
typedef __attribute__((ext_vector_type(4))) float f32x4;

__device__ __forceinline__ unsigned int fbits(float f) {
  union { float f; unsigned int u; } v; v.f = f; return v.u;
}
__device__ __forceinline__ float bcast(unsigned int u) {
  union { unsigned int u; float f; } v; v.u = u; return v.f;
}
// round-to-nearest-even bf16, returned in low 16 bits
__device__ __forceinline__ unsigned int bf16_rne(float f) {
  unsigned int b = fbits(f);
  return (b + 0x7FFFu + ((b >> 16) & 1u)) >> 16;
}

__device__ __forceinline__ float wave_red_max(float v) {
#pragma unroll
  for (int o = 32; o > 0; o >>= 1) v = fmaxf(v, __shfl_down(v, o));
  return v;
}
__device__ __forceinline__ float wave_red_sum(float v) {
#pragma unroll
  for (int o = 32; o > 0; o >>= 1) v += __shfl_down(v, o);
  return v;
}

// Fragment-ordered LDS address for a 128(row)x64(k) bf16 tile.
// Region (khalf, blk) holds a 16x32 MFMA fragment: lane = (row&15)+16*k8,
// element j = k&7 at +j*2. XOR swizzle on byte[6:4] makes staged writes
// conflict-free and keeps wave reads a bijection over each 1KB region.
__device__ __forceinline__ int frag_byte(int blk, int lane, int khalf) {
  int base = ((((khalf << 3) + blk) << 6) + lane) << 4;
  int swz = (blk ^ (lane >> 4) ^ (khalf << 2)) & 7;
  return base ^ (swz << 4);
}

// Stage a 128x64 fp32 tile (row-major, k contiguous) as bf16 hi/lo pair.
__device__ __forceinline__ void stage_hilo(const float* __restrict__ src, int row0, int k0,
                                           char* __restrict__ Lh, char* __restrict__ Ll,
                                           int t) {
#pragma unroll
  for (int i = 0; i < 8; ++i) {
    int idx = i * 256 + t;        // 0..2047 float4 units
    int r = idx >> 4, c4 = idx & 15;
    int k = c4 << 2;
    float4 f = *(const float4*)&src[(size_t)(row0 + r) * NN + k0 + k];
    unsigned int b0 = fbits(f.x), b1 = fbits(f.y), b2 = fbits(f.z), b3 = fbits(f.w);
    unsigned int h01 = (b0 >> 16) | (b1 & 0xFFFF0000u);
    unsigned int h23 = (b2 >> 16) | (b3 & 0xFFFF0000u);
    float r0 = f.x - bcast(b0 & 0xFFFF0000u);
    float r1 = f.y - bcast(b1 & 0xFFFF0000u);
    float r2 = f.z - bcast(b2 & 0xFFFF0000u);
    float r3 = f.w - bcast(b3 & 0xFFFF0000u);
    unsigned int l01 = (fbits(r0) >> 16) | (fbits(r1) & 0xFFFF0000u);
    unsigned int l23 = (fbits(r2) >> 16) | (fbits(r3) & 0xFFFF0000u);
    int khalf = k >> 5, k8 = (k >> 3) & 3, j = k & 7;
    int byte = frag_byte(r >> 4, (r & 15) + (k8 << 4), khalf) + (j << 1);
    *(uint2*)(Lh + byte) = make_uint2(h01, h23);
    *(uint2*)(Ll + byte) = make_uint2(l01, l23);
  }
}

// ---------------- Kernel 1: e = px . hx^T  (split-bf16, 3-term MFMA) -------
__global__ __launch_bounds__(256) void gemm_e(const float* __restrict__ px,
                                              const float* __restrict__ hx,
                                              float* __restrict__ e) {
  __shared__ char Ah[16384], Al[16384], Bh[16384], Bl[16384];
  const int b = blockIdx.z;
  const float* A = px + (size_t)b * NN * NN;
  const float* B = hx + (size_t)b * NN * NN;
  float* C = e + (size_t)b * NN * NN;
  const int row0 = blockIdx.y * 128, col0 = blockIdx.x * 128;
  const int t = threadIdx.x;
  const int l = t & 63, w = t >> 6;
  const int wr = w >> 1, wc = w & 1;

  f32x4 acc[4][4];
#pragma unroll
  for (int i = 0; i < 4; ++i)
#pragma unroll
    for (int j = 0; j < 4; ++j)
#pragma unroll
      for (int r = 0; r < 4; ++r) acc[i][j][r] = 0.f;

  for (int k0 = 0; k0 < NN; k0 += 64) {
    stage_hilo(A, row0, k0, Ah, Al, t);
    stage_hilo(B, col0, k0, Bh, Bl, t);
    __syncthreads();
#pragma unroll
    for (int kh = 0; kh < 2; ++kh) {
      bf16x8 ah[4], al[4], bh[4], bl[4];
#pragma unroll
      for (int i = 0; i < 4; ++i) {
        int ab = frag_byte(wr * 4 + i, l, kh);
        ah[i] = *(const bf16x8*)(Ah + ab);
        al[i] = *(const bf16x8*)(Al + ab);
        int bb = frag_byte(wc * 4 + i, l, kh);
        bh[i] = *(const bf16x8*)(Bh + bb);
        bl[i] = *(const bf16x8*)(Bl + bb);
      }
#pragma unroll
      for (int i = 0; i < 4; ++i)
#pragma unroll
        for (int j = 0; j < 4; ++j) {
          acc[i][j] = __builtin_amdgcn_mfma_f32_16x16x32_bf16(ah[i], bh[j], acc[i][j], 0, 0, 0);
          acc[i][j] = __builtin_amdgcn_mfma_f32_16x16x32_bf16(ah[i], bl[j], acc[i][j], 0, 0, 0);
          acc[i][j] = __builtin_amdgcn_mfma_f32_16x16x32_bf16(al[i], bh[j], acc[i][j], 0, 0, 0);
        }
    }
    __syncthreads();
  }
  const int g = l >> 4, li = l & 15;
#pragma unroll
  for (int i = 0; i < 4; ++i)
#pragma unroll
    for (int j = 0; j < 4; ++j)
#pragma unroll
      for (int r = 0; r < 4; ++r) {
        int row = row0 + wr * 64 + i * 16 + g * 4 + r;
        int col = col0 + wc * 64 + j * 16 + li;
        C[(size_t)row * NN + col] = acc[i][j][r];
      }
}

// -------- Kernel 2: wb = softmax_h(e + h_bias) -> bf16 [p][h] --------------
__global__ __launch_bounds__(256) void softmax_h(const float* __restrict__ e,
                                                 const int* __restrict__ h_mask,
                                                 unsigned short* __restrict__ wb) {
  const int bp = blockIdx.x;
  const int b = bp >> 9;
  const float* row = e + (size_t)bp * NN;
  unsigned short* outp = wb + (size_t)bp * NN;
  const int* hm = h_mask + (size_t)b * NN;
  const int t = threadIdx.x;
  float2 v = *(const float2*)&row[2 * t];
  int2 m = *(const int2*)&hm[2 * t];
  float v0 = m.x ? -INFINITY : v.x;
  float v1 = m.y ? -INFINITY : v.y;
  __shared__ float pm[4], ps[4];
  float mx = wave_red_max(fmaxf(v0, v1));
  if ((t & 63) == 0) pm[t >> 6] = mx;
  __syncthreads();
  mx = fmaxf(fmaxf(pm[0], pm[1]), fmaxf(pm[2], pm[3]));
  float e0 = __expf(v0 - mx), e1 = __expf(v1 - mx);
  float s = wave_red_sum(e0 + e1);
  if ((t & 63) == 0) ps[t >> 6] = s;
  __syncthreads();
  s = ps[0] + ps[1] + ps[2] + ps[3];
  float inv = 1.0f / s;
  unsigned int u0 = bf16_rne(e0 * inv), u1 = bf16_rne(e1 * inv);
  *(unsigned int*)&outp[2 * t] = u0 | (u1 << 16);
}

// ---- Kernel 3: waT[h][p] = softmax_p(e + p_bias) transposed -> bf16 -------
__global__ __launch_bounds__(256) void softmax_p(const float* __restrict__ e,
                                                 const int* __restrict__ p_mask,
                                                 unsigned short* __restrict__ waT) {
  const int b = blockIdx.y;
  const int h0 = blockIdx.x * 32;
  const int t = threadIdx.x;
  const int tx = t & 31, ty = t >> 5;
  const float* eb = e + (size_t)b * NN * NN;
  const int* pmask = p_mask + (size_t)b * NN;
  const int h = h0 + tx;
  float val[64];
  float mx = -INFINITY;
#pragma unroll
  for (int k = 0; k < 64; ++k) {
    int p = ty + (k << 3);
    float v = pmask[p] ? -INFINITY : eb[(size_t)p * NN + h];
    val[k] = v;
    mx = fmaxf(mx, v);
  }
  __shared__ float rm[8][33];
  __shared__ unsigned short tile[32][516];
  rm[ty][tx] = mx;
  __syncthreads();
  float gm = rm[0][tx];
#pragma unroll
  for (int rr = 1; rr < 8; ++rr) gm = fmaxf(gm, rm[rr][tx]);
  float s = 0.f;
#pragma unroll
  for (int k = 0; k < 64; ++k) {
    val[k] = __expf(val[k] - gm);
    s += val[k];
  }
  __syncthreads();
  rm[ty][tx] = s;
  __syncthreads();
  float gs = rm[0][tx];
#pragma unroll
  for (int rr = 1; rr < 8; ++rr) gs += rm[rr][tx];
  float inv = 1.0f / gs;
#pragma unroll
  for (int k = 0; k < 64; ++k) {
    int p = ty + (k << 3);
    tile[tx][p] = (unsigned short)bf16_rne(val[k] * inv);
  }
  __syncthreads();
  unsigned short* wt = waT + ((size_t)b * NN + h0) * NN;
#pragma unroll
  for (int i = 0; i < 16; ++i) {
    int idx = i * 256 + t;
    int r = idx >> 7, c4 = idx & 127;
    *(uint2*)&wt[(size_t)r * NN + c4 * 4] = *(const uint2*)&tile[r][c4 * 4];
  }
}

// ------ Kernel 4/5: hat = W(bf16) . B(fp32->bf16); fused 4-seg epilogue ----
__global__ __launch_bounds__(256) void gemm_wv(const unsigned short* __restrict__ Wg,
                                               const float* __restrict__ Bsrc,
                                               const float* __restrict__ Xg,
                                               float* __restrict__ outg) {
  __shared__ union {
    struct { char A[16384]; char B[16384]; } s;
    float ep[64][132];
  } u;
  const int b = blockIdx.z;
  const unsigned short* A = Wg + (size_t)b * NN * NN;
  const float* B = Bsrc + (size_t)b * NN * NN;
  const float* X = Xg + (size_t)b * NN * NN;
  float* out = outg + (size_t)b * NN * ROWC;
  const int row0 = blockIdx.y * 128, col0 = blockIdx.x * 128;
  const int t = threadIdx.x;
  const int l = t & 63, w = t >> 6;
  const int wr = w >> 1, wc = w & 1;

  f32x4 acc[4][4];
#pragma unroll
  for (int i = 0; i < 4; ++i)
#pragma unroll
    for (int j = 0; j < 4; ++j)
#pragma unroll
      for (int r = 0; r < 4; ++r) acc[i][j][r] = 0.f;

  for (int k0 = 0; k0 < NN; k0 += 64) {
    // stage A: bf16 passthrough, frag-ordered
#pragma unroll
    for (int i = 0; i < 8; ++i) {
      int idx = i * 256 + t;
      int r = idx >> 4, c4 = idx & 15, k = c4 << 2;
      uint2 v = *(const uint2*)&A[(size_t)(row0 + r) * NN + k0 + k];
      int khalf = k >> 5, k8 = (k >> 3) & 3, j = k & 7;
      int byte = frag_byte(r >> 4, (r & 15) + (k8 << 4), khalf) + (j << 1);
      *(uint2*)(u.s.A + byte) = v;
    }
    // stage B: fp32 [k][n] -> bf16, transposed into frag order (k-pairs)
#pragma unroll
    for (int i = 0; i < 4; ++i) {
      int idx = i * 256 + t;          // 0..1023
      int kp = idx >> 5, nq = idx & 31;
      int k = kp << 1, n = nq << 2;
      const float* p0 = &B[(size_t)(k0 + k) * NN + col0 + n];
      float4 f0 = *(const float4*)p0;
      float4 f1 = *(const float4*)(p0 + NN);
      int khalf = k >> 5, k8 = (k >> 3) & 3, j = k & 7;
      float fa0[4] = {f0.x, f0.y, f0.z, f0.w};
      float fa1[4] = {f1.x, f1.y, f1.z, f1.w};
#pragma unroll
      for (int c = 0; c < 4; ++c) {
        unsigned int pk = bf16_rne(fa0[c]) | (bf16_rne(fa1[c]) << 16);
        int nn2 = n + c;
        int byte = frag_byte(nn2 >> 4, (nn2 & 15) + (k8 << 4), khalf) + (j << 1);
        *(unsigned int*)(u.s.B + byte) = pk;
      }
    }
    __syncthreads();
#pragma unroll
    for (int kh = 0; kh < 2; ++kh) {
      bf16x8 av[4], bv[4];
#pragma unroll
      for (int i = 0; i < 4; ++i) {
        av[i] = *(const bf16x8*)(u.s.A + frag_byte(wr * 4 + i, l, kh));
        bv[i] = *(const bf16x8*)(u.s.B + frag_byte(wc * 4 + i, l, kh));
      }
#pragma unroll
      for (int i = 0; i < 4; ++i)
#pragma unroll
        for (int j = 0; j < 4; ++j)
          acc[i][j] = __builtin_amdgcn_mfma_f32_16x16x32_bf16(av[i], bv[j], acc[i][j], 0, 0, 0);
    }
    __syncthreads();
  }

  // epilogue: two half-tile LDS bounces -> clean float4 stores of 4 segments
  const int g = l >> 4, li = l & 15;
#pragma unroll
  for (int pass = 0; pass < 2; ++pass) {
    if (wr == pass) {
#pragma unroll
      for (int i = 0; i < 4; ++i)
#pragma unroll
        for (int j = 0; j < 4; ++j)
#pragma unroll
          for (int r = 0; r < 4; ++r)
            u.ep[i * 16 + g * 4 + r][wc * 64 + j * 16 + li] = acc[i][j][r];
    }
    __syncthreads();
#pragma unroll
    for (int i = 0; i < 8; ++i) {
      int idx = i * 256 + t;
      int r = idx >> 5, c4 = idx & 31;
      int grow = row0 + pass * 64 + r;
      float4 ph = *(const float4*)&u.ep[r][c4 * 4];
      float4 xv = *(const float4*)&X[(size_t)grow * NN + col0 + c4 * 4];
      size_t base = (size_t)grow * ROWC + col0 + c4 * 4;
      *(float4*)&out[base] = xv;
      *(float4*)&out[base + 512] = ph;
      float4 df = {xv.x - ph.x, xv.y - ph.y, xv.z - ph.z, xv.w - ph.w};
      *(float4*)&out[base + 1024] = df;
      float4 pr = {xv.x * ph.x, xv.y * ph.y, xv.z * ph.z, xv.w * ph.w};
      *(float4*)&out[base + 1536] = pr;
    }
    __syncthreads();
  }
}

extern "C" void kernel_launch(void* const* d_in, const int* in_sizes, int n_in,
                              void* d_out, int out_size, void* d_ws, size_t ws_size,
                              hipStream_t stream) {
  const float* px = (const float*)d_in[0];
  const float* hx = (const float*)d_in[1];
  const int* p_mask = (const int*)d_in[2];
  const int* h_mask = (const int*)d_in[3];
  float* out = (float*)d_out;

  float* e = (float*)d_ws;                                      // 33.5 MB fp32
  unsigned short* wb = (unsigned short*)(e + (size_t)NB * NN * NN);   // 16.8 MB bf16
  unsigned short* waT = wb + (size_t)NB * NN * NN;              // 16.8 MB bf16

  dim3 blk(256);
  dim3 gg(4, 4, NB);
  gemm_e<<<gg, blk, 0, stream>>>(px, hx, e);
  softmax_h<<<dim3(NB * NN), blk, 0, stream>>>(e, h_mask, wb);
  softmax_p<<<dim3(16, NB), blk, 0, stream>>>(e, p_mask, waT);
  gemm_wv<<<gg, blk, 0, stream>>>(wb, hx, px, out);
  gemm_wv<<<gg, blk, 0, stream>>>(waT, px, hx, out + (size_t)NB * NN * ROWC);
}

// Round 3
// 214.759 us; speedup vs baseline: 2.1559x; 1.1297x over previous
//
#include <hip/hip_runtime.h>
#include <math.h>

#define NB 32
#define NN 512
#define ROWC 2048ull

typedef __attribute__((ext_vector_type(8))) short bf16x8;
typedef __attribute__((ext_vector_type(4))) float f32x4;

__device__ __forceinline__ unsigned int fbits(float f) {
  union { float f; unsigned int u; } v; v.f = f; return v.u;
}
__device__ __forceinline__ float bcast(unsigned int u) {
  union { unsigned int u; float f; } v; v.u = u; return v.f;
}
// round-to-nearest-even bf16, returned in low 16 bits
__device__ __forceinline__ unsigned int bf16_rne(float f) {
  unsigned int b = fbits(f);
  return (b + 0x7FFFu + ((b >> 16) & 1u)) >> 16;
}

// Fragment-ordered LDS address for a 128(row)x64(k) bf16 tile.
// Region (khalf, blk) holds a 16x32 MFMA fragment: lane = (row&15)+16*k8,
// element j = k&7 at +j*2. XOR swizzle on byte[6:4] keeps staged writes
// conflict-free; reads are a bijection within each 1KB region.
__device__ __forceinline__ int frag_byte(int blk, int lane, int khalf) {
  int base = ((((khalf << 3) + blk) << 6) + lane) << 4;
  int swz = (blk ^ (lane >> 4) ^ (khalf << 2)) & 7;
  return base ^ (swz << 4);
}

// Stage a 128x64 fp32 tile (row-major, k contiguous) as bf16 hi/lo pair.
__device__ __forceinline__ void stage_hilo(const float* __restrict__ src, int row0, int k0,
                                           char* __restrict__ Lh, char* __restrict__ Ll,
                                           int t) {
#pragma unroll
  for (int i = 0; i < 8; ++i) {
    int idx = i * 256 + t;        // 0..2047 float4 units
    int r = idx >> 4, c4 = idx & 15;
    int k = c4 << 2;
    float4 f = *(const float4*)&src[(size_t)(row0 + r) * NN + k0 + k];
    unsigned int b0 = fbits(f.x), b1 = fbits(f.y), b2 = fbits(f.z), b3 = fbits(f.w);
    unsigned int h01 = (b0 >> 16) | (b1 & 0xFFFF0000u);
    unsigned int h23 = (b2 >> 16) | (b3 & 0xFFFF0000u);
    float r0 = f.x - bcast(b0 & 0xFFFF0000u);
    float r1 = f.y - bcast(b1 & 0xFFFF0000u);
    float r2 = f.z - bcast(b2 & 0xFFFF0000u);
    float r3 = f.w - bcast(b3 & 0xFFFF0000u);
    unsigned int l01 = (fbits(r0) >> 16) | (fbits(r1) & 0xFFFF0000u);
    unsigned int l23 = (fbits(r2) >> 16) | (fbits(r3) & 0xFFFF0000u);
    int khalf = k >> 5, k8 = (k >> 3) & 3, j = k & 7;
    int byte = frag_byte(r >> 4, (r & 15) + (k8 << 4), khalf) + (j << 1);
    *(uint2*)(Lh + byte) = make_uint2(h01, h23);
    *(uint2*)(Ll + byte) = make_uint2(l01, l23);
  }
}

// --- Kernel 1: e = px.hx^T (split-bf16 MFMA) + masked row/col softmax stats -
__global__ __launch_bounds__(256) void gemm_e_stats(
    const float* __restrict__ px, const float* __restrict__ hx,
    const int* __restrict__ p_mask, const int* __restrict__ h_mask,
    float* __restrict__ e,
    float* __restrict__ rpm, float* __restrict__ rps,
    float* __restrict__ cpm, float* __restrict__ cps) {
  __shared__ char Ah[16384], Al[16384], Bh[16384], Bl[16384];
  __shared__ int pmk[128], hmk[128];
  __shared__ float st_m[2][128], st_s[2][128], sc_m[2][128], sc_s[2][128];
  const int b = blockIdx.z;
  const float* A = px + (size_t)b * NN * NN;
  const float* B = hx + (size_t)b * NN * NN;
  float* C = e + (size_t)b * NN * NN;
  const int row0 = blockIdx.y * 128, col0 = blockIdx.x * 128;
  const int t = threadIdx.x;
  const int l = t & 63, w = t >> 6;
  const int wr = w >> 1, wc = w & 1;
  const int g = l >> 4, li = l & 15;

  if (t < 128) pmk[t] = p_mask[(size_t)b * NN + row0 + t];
  else hmk[t - 128] = h_mask[(size_t)b * NN + col0 + (t - 128)];

  f32x4 acc[4][4];
#pragma unroll
  for (int i = 0; i < 4; ++i)
#pragma unroll
    for (int j = 0; j < 4; ++j)
#pragma unroll
      for (int r = 0; r < 4; ++r) acc[i][j][r] = 0.f;

  for (int k0 = 0; k0 < NN; k0 += 64) {
    stage_hilo(A, row0, k0, Ah, Al, t);
    stage_hilo(B, col0, k0, Bh, Bl, t);
    __syncthreads();
#pragma unroll
    for (int kh = 0; kh < 2; ++kh) {
      bf16x8 ah[4], al[4], bh[4], bl[4];
#pragma unroll
      for (int i = 0; i < 4; ++i) {
        int ab = frag_byte(wr * 4 + i, l, kh);
        ah[i] = *(const bf16x8*)(Ah + ab);
        al[i] = *(const bf16x8*)(Al + ab);
        int bb = frag_byte(wc * 4 + i, l, kh);
        bh[i] = *(const bf16x8*)(Bh + bb);
        bl[i] = *(const bf16x8*)(Bl + bb);
      }
#pragma unroll
      for (int i = 0; i < 4; ++i)
#pragma unroll
        for (int j = 0; j < 4; ++j) {
          acc[i][j] = __builtin_amdgcn_mfma_f32_16x16x32_bf16(ah[i], bh[j], acc[i][j], 0, 0, 0);
          acc[i][j] = __builtin_amdgcn_mfma_f32_16x16x32_bf16(ah[i], bl[j], acc[i][j], 0, 0, 0);
          acc[i][j] = __builtin_amdgcn_mfma_f32_16x16x32_bf16(al[i], bh[j], acc[i][j], 0, 0, 0);
        }
    }
    __syncthreads();
  }

  // write e
#pragma unroll
  for (int i = 0; i < 4; ++i)
#pragma unroll
    for (int j = 0; j < 4; ++j)
#pragma unroll
      for (int r = 0; r < 4; ++r) {
        int row = row0 + wr * 64 + i * 16 + g * 4 + r;
        int col = col0 + wc * 64 + j * 16 + li;
        C[(size_t)row * NN + col] = acc[i][j][r];
      }

  // ---- row stats (softmax over h): max & sum(exp) over this block's 128 cols
#pragma unroll
  for (int i = 0; i < 4; ++i)
#pragma unroll
    for (int r = 0; r < 4; ++r) {
      float v[4];
      float m = -INFINITY;
#pragma unroll
      for (int j = 0; j < 4; ++j) {
        v[j] = hmk[wc * 64 + j * 16 + li] ? -INFINITY : acc[i][j][r];
        m = fmaxf(m, v[j]);
      }
#pragma unroll
      for (int o = 1; o < 16; o <<= 1) m = fmaxf(m, __shfl_xor(m, o));
      float s = 0.f;
#pragma unroll
      for (int j = 0; j < 4; ++j) s += (v[j] == -INFINITY) ? 0.f : __expf(v[j] - m);
#pragma unroll
      for (int o = 1; o < 16; o <<= 1) s += __shfl_xor(s, o);
      if (li == 0) {
        st_m[wc][wr * 64 + i * 16 + g * 4 + r] = m;
        st_s[wc][wr * 64 + i * 16 + g * 4 + r] = s;
      }
    }

  // ---- col stats (softmax over p): max & sum(exp) over this block's 128 rows
#pragma unroll
  for (int j = 0; j < 4; ++j) {
    float v[16];
    float m = -INFINITY;
#pragma unroll
    for (int i = 0; i < 4; ++i)
#pragma unroll
      for (int r = 0; r < 4; ++r) {
        float x = pmk[wr * 64 + i * 16 + g * 4 + r] ? -INFINITY : acc[i][j][r];
        v[i * 4 + r] = x;
        m = fmaxf(m, x);
      }
    m = fmaxf(m, __shfl_xor(m, 16));
    m = fmaxf(m, __shfl_xor(m, 32));
    float s = 0.f;
#pragma unroll
    for (int q = 0; q < 16; ++q) s += (v[q] == -INFINITY) ? 0.f : __expf(v[q] - m);
    s += __shfl_xor(s, 16);
    s += __shfl_xor(s, 32);
    if (g == 0) {
      sc_m[wr][wc * 64 + j * 16 + li] = m;
      sc_s[wr][wc * 64 + j * 16 + li] = s;
    }
  }
  __syncthreads();

  if (t < 128) {
    float m0 = st_m[0][t], m1 = st_m[1][t];
    float s0 = st_s[0][t], s1 = st_s[1][t];
    float m = fmaxf(m0, m1);
    float s = 0.f;
    if (s0 > 0.f) s += s0 * __expf(m0 - m);
    if (s1 > 0.f) s += s1 * __expf(m1 - m);
    rpm[((size_t)b * 4 + blockIdx.x) * NN + row0 + t] = m;
    rps[((size_t)b * 4 + blockIdx.x) * NN + row0 + t] = s;
  } else {
    int c = t - 128;
    float m0 = sc_m[0][c], m1 = sc_m[1][c];
    float s0 = sc_s[0][c], s1 = sc_s[1][c];
    float m = fmaxf(m0, m1);
    float s = 0.f;
    if (s0 > 0.f) s += s0 * __expf(m0 - m);
    if (s1 > 0.f) s += s1 * __expf(m1 - m);
    cpm[((size_t)b * 4 + blockIdx.y) * NN + col0 + c] = m;
    cps[((size_t)b * 4 + blockIdx.y) * NN + col0 + c] = s;
  }
}

// --- Kernel 2: merge 4 partials per row/col (online-softmax merge) ---------
__global__ __launch_bounds__(512) void merge_stats(
    const float* __restrict__ rpm, const float* __restrict__ rps,
    const float* __restrict__ cpm, const float* __restrict__ cps,
    float* __restrict__ rmax, float* __restrict__ rinv,
    float* __restrict__ cmax, float* __restrict__ cinv) {
  const int b = blockIdx.x;
  const int t = threadIdx.x;
  const float* pm = blockIdx.y == 0 ? rpm : cpm;
  const float* ps = blockIdx.y == 0 ? rps : cps;
  float* fm = blockIdx.y == 0 ? rmax : cmax;
  float* fi = blockIdx.y == 0 ? rinv : cinv;
  float mj[4], sj[4];
  float m = -INFINITY;
#pragma unroll
  for (int j = 0; j < 4; ++j) {
    mj[j] = pm[((size_t)b * 4 + j) * NN + t];
    sj[j] = ps[((size_t)b * 4 + j) * NN + t];
    m = fmaxf(m, mj[j]);
  }
  float s = 0.f;
#pragma unroll
  for (int j = 0; j < 4; ++j)
    if (sj[j] > 0.f) s += sj[j] * __expf(mj[j] - m);
  fm[(size_t)b * NN + t] = m;
  fi[(size_t)b * NN + t] = 1.0f / s;
}

// --- Kernel 3: m_p : px_hat = softmax_h(e) @ hx, weights computed on the fly
__global__ __launch_bounds__(256) void gemm_wp(
    const float* __restrict__ E, const float* __restrict__ hxg,
    const float* __restrict__ pxg, const int* __restrict__ h_mask,
    const float* __restrict__ rmax, const float* __restrict__ rinv,
    float* __restrict__ outg) {
  __shared__ union {
    struct { char A[16384]; char B[16384]; } s;
    float ep[64][132];
  } u;
  const int b = blockIdx.z;
  const float* Eb = E + (size_t)b * NN * NN;
  const float* B = hxg + (size_t)b * NN * NN;
  const float* X = pxg + (size_t)b * NN * NN;
  const int* hm = h_mask + (size_t)b * NN;
  const float* rmx = rmax + (size_t)b * NN;
  const float* rin = rinv + (size_t)b * NN;
  float* out = outg + (size_t)b * NN * ROWC;
  const int row0 = blockIdx.y * 128, col0 = blockIdx.x * 128;
  const int t = threadIdx.x;
  const int l = t & 63, w = t >> 6;
  const int wr = w >> 1, wc = w & 1;

  float rmv[8];
#pragma unroll
  for (int i = 0; i < 8; ++i) rmv[i] = rmx[row0 + ((i * 256 + t) >> 4)];

  f32x4 acc[4][4];
#pragma unroll
  for (int i = 0; i < 4; ++i)
#pragma unroll
    for (int j = 0; j < 4; ++j)
#pragma unroll
      for (int r = 0; r < 4; ++r) acc[i][j][r] = 0.f;

  for (int k0 = 0; k0 < NN; k0 += 64) {
    // stage A: w = exp(e - rowmax), masked h -> 0, to bf16 frag order
#pragma unroll
    for (int i = 0; i < 8; ++i) {
      int idx = i * 256 + t;
      int r = idx >> 4, c4 = idx & 15, k = c4 << 2;
      float4 f = *(const float4*)&Eb[(size_t)(row0 + r) * NN + k0 + k];
      int4 m4 = *(const int4*)&hm[k0 + k];
      float w0 = m4.x ? 0.f : __expf(f.x - rmv[i]);
      float w1 = m4.y ? 0.f : __expf(f.y - rmv[i]);
      float w2 = m4.z ? 0.f : __expf(f.z - rmv[i]);
      float w3 = m4.w ? 0.f : __expf(f.w - rmv[i]);
      unsigned int p01 = bf16_rne(w0) | (bf16_rne(w1) << 16);
      unsigned int p23 = bf16_rne(w2) | (bf16_rne(w3) << 16);
      int khalf = k >> 5, k8 = (k >> 3) & 3, j = k & 7;
      int byte = frag_byte(r >> 4, (r & 15) + (k8 << 4), khalf) + (j << 1);
      *(uint2*)(u.s.A + byte) = make_uint2(p01, p23);
    }
    // stage B: hx fp32 [k][n] -> bf16, transposed into frag order (k-pairs)
#pragma unroll
    for (int i = 0; i < 4; ++i) {
      int idx = i * 256 + t;
      int kp = idx >> 5, nq = idx & 31;
      int k = kp << 1, n = nq << 2;
      const float* p0 = &B[(size_t)(k0 + k) * NN + col0 + n];
      float4 f0 = *(const float4*)p0;
      float4 f1 = *(const float4*)(p0 + NN);
      int khalf = k >> 5, k8 = (k >> 3) & 3, j = k & 7;
      float fa0[4] = {f0.x, f0.y, f0.z, f0.w};
      float fa1[4] = {f1.x, f1.y, f1.z, f1.w};
#pragma unroll
      for (int c = 0; c < 4; ++c) {
        unsigned int pk = bf16_rne(fa0[c]) | (bf16_rne(fa1[c]) << 16);
        int nn2 = n + c;
        int byte = frag_byte(nn2 >> 4, (nn2 & 15) + (k8 << 4), khalf) + (j << 1);
        *(unsigned int*)(u.s.B + byte) = pk;
      }
    }
    __syncthreads();
#pragma unroll
    for (int kh = 0; kh < 2; ++kh) {
      bf16x8 av[4], bv[4];
#pragma unroll
      for (int i = 0; i < 4; ++i) {
        av[i] = *(const bf16x8*)(u.s.A + frag_byte(wr * 4 + i, l, kh));
        bv[i] = *(const bf16x8*)(u.s.B + frag_byte(wc * 4 + i, l, kh));
      }
#pragma unroll
      for (int i = 0; i < 4; ++i)
#pragma unroll
        for (int j = 0; j < 4; ++j)
          acc[i][j] = __builtin_amdgcn_mfma_f32_16x16x32_bf16(av[i], bv[j], acc[i][j], 0, 0, 0);
    }
    __syncthreads();
  }

  const int g = l >> 4, li = l & 15;
#pragma unroll
  for (int pass = 0; pass < 2; ++pass) {
    if (wr == pass) {
#pragma unroll
      for (int i = 0; i < 4; ++i)
#pragma unroll
        for (int j = 0; j < 4; ++j)
#pragma unroll
          for (int r = 0; r < 4; ++r)
            u.ep[i * 16 + g * 4 + r][wc * 64 + j * 16 + li] = acc[i][j][r];
    }
    __syncthreads();
#pragma unroll
    for (int i = 0; i < 8; ++i) {
      int idx = i * 256 + t;
      int r = idx >> 5, c4 = idx & 31;
      int grow = row0 + pass * 64 + r;
      float ri = rin[grow];
      float4 ph = *(const float4*)&u.ep[r][c4 * 4];
      ph.x *= ri; ph.y *= ri; ph.z *= ri; ph.w *= ri;
      float4 xv = *(const float4*)&X[(size_t)grow * NN + col0 + c4 * 4];
      size_t base = (size_t)grow * ROWC + col0 + c4 * 4;
      *(float4*)&out[base] = xv;
      *(float4*)&out[base + 512] = ph;
      float4 df = {xv.x - ph.x, xv.y - ph.y, xv.z - ph.z, xv.w - ph.w};
      *(float4*)&out[base + 1024] = df;
      float4 pr = {xv.x * ph.x, xv.y * ph.y, xv.z * ph.z, xv.w * ph.w};
      *(float4*)&out[base + 1536] = pr;
    }
    __syncthreads();
  }
}

// --- Kernel 4: m_h : hx_hat = softmax_p(e)^T @ px, weights on the fly ------
__global__ __launch_bounds__(256) void gemm_wh(
    const float* __restrict__ E, const float* __restrict__ pxg,
    const float* __restrict__ hxg, const int* __restrict__ p_mask,
    const float* __restrict__ cmax, const float* __restrict__ cinv,
    float* __restrict__ outg) {
  __shared__ union {
    struct { char A[16384]; char B[16384]; } s;
    float ep[64][132];
  } u;
  const int b = blockIdx.z;
  const float* Eb = E + (size_t)b * NN * NN;
  const float* B = pxg + (size_t)b * NN * NN;
  const float* X = hxg + (size_t)b * NN * NN;
  const int* pmsk = p_mask + (size_t)b * NN;
  const float* cmx = cmax + (size_t)b * NN;
  const float* cin = cinv + (size_t)b * NN;
  float* out = outg + (size_t)b * NN * ROWC;
  const int row0 = blockIdx.y * 128, col0 = blockIdx.x * 128;  // rows = h
  const int t = threadIdx.x;
  const int l = t & 63, w = t >> 6;
  const int wr = w >> 1, wc = w & 1;

  float4 cmv[4];
#pragma unroll
  for (int i = 0; i < 4; ++i) {
    int idx = i * 256 + t;
    int n = (idx & 31) << 2;
    cmv[i] = *(const float4*)&cmx[row0 + n];
  }

  f32x4 acc[4][4];
#pragma unroll
  for (int i = 0; i < 4; ++i)
#pragma unroll
    for (int j = 0; j < 4; ++j)
#pragma unroll
      for (int r = 0; r < 4; ++r) acc[i][j][r] = 0.f;

  for (int k0 = 0; k0 < NN; k0 += 64) {
    // stage A: w[h][p] = exp(e[p][h] - colmax[h]), masked p -> 0 (k-pairs)
#pragma unroll
    for (int i = 0; i < 4; ++i) {
      int idx = i * 256 + t;
      int kp = idx >> 5, nq = idx & 31;
      int k = kp << 1, n = nq << 2;
      const float* p0 = &Eb[(size_t)(k0 + k) * NN + row0 + n];
      float4 f0 = *(const float4*)p0;
      float4 f1 = *(const float4*)(p0 + NN);
      int pm0 = pmsk[k0 + k], pm1 = pmsk[k0 + k + 1];
      float fa0[4] = {f0.x, f0.y, f0.z, f0.w};
      float fa1[4] = {f1.x, f1.y, f1.z, f1.w};
      float cma[4] = {cmv[i].x, cmv[i].y, cmv[i].z, cmv[i].w};
      int khalf = k >> 5, k8 = (k >> 3) & 3, j = k & 7;
#pragma unroll
      for (int c = 0; c < 4; ++c) {
        float w0 = pm0 ? 0.f : __expf(fa0[c] - cma[c]);
        float w1 = pm1 ? 0.f : __expf(fa1[c] - cma[c]);
        unsigned int pk = bf16_rne(w0) | (bf16_rne(w1) << 16);
        int nn2 = n + c;
        int byte = frag_byte(nn2 >> 4, (nn2 & 15) + (k8 << 4), khalf) + (j << 1);
        *(unsigned int*)(u.s.A + byte) = pk;
      }
    }
    // stage B: px fp32 [k][n] -> bf16 frag order (k-pairs)
#pragma unroll
    for (int i = 0; i < 4; ++i) {
      int idx = i * 256 + t;
      int kp = idx >> 5, nq = idx & 31;
      int k = kp << 1, n = nq << 2;
      const float* p0 = &B[(size_t)(k0 + k) * NN + col0 + n];
      float4 f0 = *(const float4*)p0;
      float4 f1 = *(const float4*)(p0 + NN);
      int khalf = k >> 5, k8 = (k >> 3) & 3, j = k & 7;
      float fa0[4] = {f0.x, f0.y, f0.z, f0.w};
      float fa1[4] = {f1.x, f1.y, f1.z, f1.w};
#pragma unroll
      for (int c = 0; c < 4; ++c) {
        unsigned int pk = bf16_rne(fa0[c]) | (bf16_rne(fa1[c]) << 16);
        int nn2 = n + c;
        int byte = frag_byte(nn2 >> 4, (nn2 & 15) + (k8 << 4), khalf) + (j << 1);
        *(unsigned int*)(u.s.B + byte) = pk;
      }
    }
    __syncthreads();
#pragma unroll
    for (int kh = 0; kh < 2; ++kh) {
      bf16x8 av[4], bv[4];
#pragma unroll
      for (int i = 0; i < 4; ++i) {
        av[i] = *(const bf16x8*)(u.s.A + frag_byte(wr * 4 + i, l, kh));
        bv[i] = *(const bf16x8*)(u.s.B + frag_byte(wc * 4 + i, l, kh));
      }
#pragma unroll
      for (int i = 0; i < 4; ++i)
#pragma unroll
        for (int j = 0; j < 4; ++j)
          acc[i][j] = __builtin_amdgcn_mfma_f32_16x16x32_bf16(av[i], bv[j], acc[i][j], 0, 0, 0);
    }
    __syncthreads();
  }

  const int g = l >> 4, li = l & 15;
#pragma unroll
  for (int pass = 0; pass < 2; ++pass) {
    if (wr == pass) {
#pragma unroll
      for (int i = 0; i < 4; ++i)
#pragma unroll
        for (int j = 0; j < 4; ++j)
#pragma unroll
          for (int r = 0; r < 4; ++r)
            u.ep[i * 16 + g * 4 + r][wc * 64 + j * 16 + li] = acc[i][j][r];
    }
    __syncthreads();
#pragma unroll
    for (int i = 0; i < 8; ++i) {
      int idx = i * 256 + t;
      int r = idx >> 5, c4 = idx & 31;
      int grow = row0 + pass * 64 + r;  // h
      float ci = cin[grow];
      float4 hh = *(const float4*)&u.ep[r][c4 * 4];
      hh.x *= ci; hh.y *= ci; hh.z *= ci; hh.w *= ci;
      float4 xv = *(const float4*)&X[(size_t)grow * NN + col0 + c4 * 4];
      size_t base = (size_t)grow * ROWC + col0 + c4 * 4;
      *(float4*)&out[base] = xv;
      *(float4*)&out[base + 512] = hh;
      float4 df = {xv.x - hh.x, xv.y - hh.y, xv.z - hh.z, xv.w - hh.w};
      *(float4*)&out[base + 1024] = df;
      float4 pr = {xv.x * hh.x, xv.y * hh.y, xv.z * hh.z, xv.w * hh.w};
      *(float4*)&out[base + 1536] = pr;
    }
    __syncthreads();
  }
}

extern "C" void kernel_launch(void* const* d_in, const int* in_sizes, int n_in,
                              void* d_out, int out_size, void* d_ws, size_t ws_size,
                              hipStream_t stream) {
  const float* px = (const float*)d_in[0];
  const float* hx = (const float*)d_in[1];
  const int* p_mask = (const int*)d_in[2];
  const int* h_mask = (const int*)d_in[3];
  float* out = (float*)d_out;

  float* E = (float*)d_ws;                         // 33.5 MB fp32
  float* rpm = E + (size_t)NB * NN * NN;           // [B][4][NN] partial row max
  float* rps = rpm + (size_t)NB * 4 * NN;
  float* cpm = rps + (size_t)NB * 4 * NN;
  float* cps = cpm + (size_t)NB * 4 * NN;
  float* rmaxv = cps + (size_t)NB * 4 * NN;        // [B][NN] finals
  float* rinvv = rmaxv + (size_t)NB * NN;
  float* cmaxv = rinvv + (size_t)NB * NN;
  float* cinvv = cmaxv + (size_t)NB * NN;

  dim3 blk(256);
  dim3 gg(4, 4, NB);
  gemm_e_stats<<<gg, blk, 0, stream>>>(px, hx, p_mask, h_mask, E, rpm, rps, cpm, cps);
  merge_stats<<<dim3(NB, 2), dim3(512), 0, stream>>>(rpm, rps, cpm, cps,
                                                     rmaxv, rinvv, cmaxv, cinvv);
  gemm_wp<<<gg, blk, 0, stream>>>(E, hx, px, h_mask, rmaxv, rinvv, out);
  gemm_wh<<<gg, blk, 0, stream>>>(E, px, hx, p_mask, cmaxv, cinvv,
                                  out + (size_t)NB * NN * ROWC);
}